// Round 2
// baseline (487.583 us; speedup 1.0000x reference)
//
#include <hip/hip_runtime.h>
#include <hip/hip_bf16.h>
#include <math.h>
#include <type_traits>

typedef __bf16 bf16_t;
typedef __bf16 bf16x4 __attribute__((ext_vector_type(4)));
typedef __bf16 bf16x8 __attribute__((ext_vector_type(8)));
typedef float  f32x4  __attribute__((ext_vector_type(4)));

#define WPB 4    // waves per block
#define XS  76   // x-scratch row stride (bf16 elements): 152 B, 8B-aligned, conflict-free
#define RS  20   // rgb-scratch row stride (elements of T)

// MFMA 16x16x32 layouts (m89/m120-verified):
//   A: lane(m = lane&15, q = lane>>4) holds A[m][8q+j], j=0..7
//   B: lane(n = lane&15, q)           holds B[8q+j][n]
//   C: lane(n = lane&15, q) reg r     holds C[4q+r][n]

// ---------------- dtype detector ----------------
// Xavier weights have |w| <= 0.25. If W0 is stored bf16, every 16-bit word has
// exponent field <= 125. If W0 is stored fp32, the EVEN 16-bit words are low
// mantissa halves -> uniform exponent field -> ~49% decode to |bf16| >= 8.
__global__ void detect_dtype_kernel(const unsigned short* __restrict__ w0_raw,
                                    int* __restrict__ flag) {
    if (threadIdx.x == 0 && blockIdx.x == 0) {
        int big = 0;
        for (int i = 0; i < 512; i += 2) {          // even words of first 1024 B
            unsigned e = (w0_raw[i] >> 7) & 0xFFu;  // bf16 exponent field
            big += (e >= 130u);                     // |value| >= 8
        }
        *flag = (big > 8) ? 1 : 0;                  // 1 => inputs are float32
    }
}

// ---------------- load helpers ----------------
template<typename T>
__device__ __forceinline__ bf16x8 load_row8(const T* p) {
    if constexpr (std::is_same<T, float>::value) {
        f32x4 lo = *(const f32x4*)p;
        f32x4 hi = *(const f32x4*)(p + 4);
        bf16x8 r;
        #pragma unroll
        for (int j = 0; j < 4; ++j) { r[j] = (bf16_t)lo[j]; r[j + 4] = (bf16_t)hi[j]; }
        return r;
    } else {
        return *(const bf16x8*)p;
    }
}

// ---------------- main body (templated on I/O dtype) ----------------
template<typename T>
__device__ __forceinline__ void run_mlp(
    const T* __restrict__ feat, const T* __restrict__ W0, const T* __restrict__ b0,
    const T* __restrict__ W1, const T* __restrict__ b1, const T* __restrict__ Ws,
    const T* __restrict__ bs, const T* __restrict__ Wr, const T* __restrict__ br,
    T* __restrict__ out_sigma, T* __restrict__ out_rgb,
    int num_tiles, int wave_stride, int gw, bf16_t* xs, T* rs)
{
    const int lane = threadIdx.x & 63;
    const int n    = lane & 15;
    const int q    = lane >> 4;

    // ---- one-time weight fragment construction (L2-resident) ----
    bf16x8 w0f[4];                       // W0 [32 x 64], B-frags
    #pragma unroll
    for (int t = 0; t < 4; ++t)
        #pragma unroll
        for (int j = 0; j < 8; ++j)
            w0f[t][j] = (bf16_t)(float)W0[(8*q + j)*64 + 16*t + n];

    bf16x8 w1f[4][2];                    // W1 [64 x 64], 4 col-tiles x 2 K-chunks
    #pragma unroll
    for (int t = 0; t < 4; ++t)
        #pragma unroll
        for (int c = 0; c < 2; ++c)
            #pragma unroll
            for (int j = 0; j < 8; ++j)
                w1f[t][c][j] = (bf16_t)(float)W1[(32*c + 8*q + j)*64 + 16*t + n];

    bf16x8 whf[2][2];                    // heads: tile0 = Wr (16 cols), tile1 col0 = Ws
    #pragma unroll
    for (int c = 0; c < 2; ++c)
        #pragma unroll
        for (int j = 0; j < 8; ++j) {
            whf[0][c][j] = (bf16_t)(float)Wr[(32*c + 8*q + j)*16 + n];
            whf[1][c][j] = (n == 0) ? (bf16_t)(float)Ws[32*c + 8*q + j] : (bf16_t)0.0f;
        }

    float b0v[4], b1v[4];
    #pragma unroll
    for (int t = 0; t < 4; ++t) {
        b0v[t] = (float)b0[16*t + n];
        b1v[t] = (float)b1[16*t + n];
    }
    const float brv = (float)br[n];
    const float bsv = (n == 0) ? ((float)bs[0] - 1.0f) : 0.0f;   // fold the -1 shift

    int tile = gw;
    if (tile >= num_tiles) return;

    bf16x8 a0 = load_row8(feat + (size_t)(tile*16 + n)*32 + 8*q);

    while (true) {
        const int  nxt  = tile + wave_stride;
        const bool more = (nxt < num_tiles);
        const int  pf   = more ? nxt : tile;
        bf16x8 a0n = load_row8(feat + (size_t)(pf*16 + n)*32 + 8*q);

        const int rowbase = tile * 16;

        // ---- layer 0 ----
        f32x4 acc0[4];
        #pragma unroll
        for (int t = 0; t < 4; ++t) {
            acc0[t] = (f32x4){b0v[t], b0v[t], b0v[t], b0v[t]};
            acc0[t] = __builtin_amdgcn_mfma_f32_16x16x32_bf16(a0, w0f[t], acc0[t], 0, 0, 0);
        }
        #pragma unroll
        for (int t = 0; t < 4; ++t)
            #pragma unroll
            for (int r = 0; r < 4; ++r)
                xs[(4*q + r)*XS + 16*t + n] = (bf16_t)fmaxf(acc0[t][r], 0.0f);

        bf16x8 a1[2];
        #pragma unroll
        for (int c = 0; c < 2; ++c) {
            union { bf16x8 v; struct { bf16x4 lo, hi; } h; } u;
            u.h.lo = *(const bf16x4*)&xs[n*XS + 32*c + 8*q];
            u.h.hi = *(const bf16x4*)&xs[n*XS + 32*c + 8*q + 4];
            a1[c] = u.v;
        }

        // ---- layer 1 ----
        f32x4 acc1[4];
        #pragma unroll
        for (int t = 0; t < 4; ++t) {
            acc1[t] = (f32x4){b1v[t], b1v[t], b1v[t], b1v[t]};
            acc1[t] = __builtin_amdgcn_mfma_f32_16x16x32_bf16(a1[0], w1f[t][0], acc1[t], 0, 0, 0);
            acc1[t] = __builtin_amdgcn_mfma_f32_16x16x32_bf16(a1[1], w1f[t][1], acc1[t], 0, 0, 0);
        }
        #pragma unroll
        for (int t = 0; t < 4; ++t)
            #pragma unroll
            for (int r = 0; r < 4; ++r)
                xs[(4*q + r)*XS + 16*t + n] = (bf16_t)fmaxf(acc1[t][r], 0.0f);

        bf16x8 ah[2];
        #pragma unroll
        for (int c = 0; c < 2; ++c) {
            union { bf16x8 v; struct { bf16x4 lo, hi; } h; } u;
            u.h.lo = *(const bf16x4*)&xs[n*XS + 32*c + 8*q];
            u.h.hi = *(const bf16x4*)&xs[n*XS + 32*c + 8*q + 4];
            ah[c] = u.v;
        }

        // ---- heads ----
        f32x4 aR = (f32x4){brv, brv, brv, brv};
        aR = __builtin_amdgcn_mfma_f32_16x16x32_bf16(ah[0], whf[0][0], aR, 0, 0, 0);
        aR = __builtin_amdgcn_mfma_f32_16x16x32_bf16(ah[1], whf[0][1], aR, 0, 0, 0);
        f32x4 aS = (f32x4){bsv, bsv, bsv, bsv};
        aS = __builtin_amdgcn_mfma_f32_16x16x32_bf16(ah[0], whf[1][0], aS, 0, 0, 0);
        aS = __builtin_amdgcn_mfma_f32_16x16x32_bf16(ah[1], whf[1][1], aS, 0, 0, 0);

        // ---- rgb epilogue: repack via LDS -> coalesced vector stores ----
        #pragma unroll
        for (int r = 0; r < 4; ++r)
            rs[(4*q + r)*RS + n] = (T)aR[r];
        if constexpr (std::is_same<T, float>::value) {
            f32x4 v = *(const f32x4*)&rs[(lane >> 2)*RS + (lane & 3)*4];
            *(f32x4*)(out_rgb + (size_t)rowbase*16 + 4*lane) = v;
        } else {
            bf16x4 v = *(const bf16x4*)&rs[(lane >> 2)*RS + (lane & 3)*4];
            *(bf16x4*)(out_rgb + (size_t)rowbase*16 + 4*lane) = v;
        }

        // ---- sigma epilogue: softplus ----
        if (n == 0) {
            if constexpr (std::is_same<T, float>::value) {
                f32x4 p4;
                #pragma unroll
                for (int r = 0; r < 4; ++r) {
                    float z  = aS[r];
                    p4[r] = fmaxf(z, 0.0f) + log1pf(expf(-fabsf(z)));
                }
                *(f32x4*)(out_sigma + (size_t)rowbase + 4*q) = p4;
            } else {
                bf16x4 p4;
                #pragma unroll
                for (int r = 0; r < 4; ++r) {
                    float z  = aS[r];
                    p4[r] = (bf16_t)(fmaxf(z, 0.0f) + log1pf(expf(-fabsf(z))));
                }
                *(bf16x4*)(out_sigma + (size_t)rowbase + 4*q) = p4;
            }
        }

        if (!more) break;
        tile = nxt;
        a0   = a0n;
    }
}

__global__ __launch_bounds__(256)
void ngp_mlp_kernel(const void* feat, const void* W0, const void* b0,
                    const void* W1, const void* b1, const void* Ws,
                    const void* bs, const void* Wr, const void* br,
                    void* out, const int* __restrict__ flag,
                    int num_tiles, int wave_stride)
{
    __shared__ __align__(16) bf16_t xs_all[WPB][16 * XS];
    __shared__ __align__(16) float  rs_all[WPB][16 * RS];

    const int wid = threadIdx.x >> 6;
    const int gw  = blockIdx.x * WPB + wid;
    const int B   = num_tiles * 16;
    const int is_f32 = *flag;   // wave-uniform scalar branch

    if (is_f32) {
        float* out_sigma = (float*)out;
        run_mlp<float>((const float*)feat, (const float*)W0, (const float*)b0,
                       (const float*)W1, (const float*)b1, (const float*)Ws,
                       (const float*)bs, (const float*)Wr, (const float*)br,
                       out_sigma, out_sigma + B, num_tiles, wave_stride, gw,
                       xs_all[wid], rs_all[wid]);
    } else {
        bf16_t* out_sigma = (bf16_t*)out;
        run_mlp<bf16_t>((const bf16_t*)feat, (const bf16_t*)W0, (const bf16_t*)b0,
                        (const bf16_t*)W1, (const bf16_t*)b1, (const bf16_t*)Ws,
                        (const bf16_t*)bs, (const bf16_t*)Wr, (const bf16_t*)br,
                        out_sigma, out_sigma + B, num_tiles, wave_stride, gw,
                        xs_all[wid], (bf16_t*)rs_all[wid]);
    }
}

extern "C" void kernel_launch(void* const* d_in, const int* in_sizes, int n_in,
                              void* d_out, int out_size, void* d_ws, size_t ws_size,
                              hipStream_t stream) {
    const int B         = in_sizes[0] / 32;      // 2,097,152
    const int num_tiles = B / 16;                // 131,072
    int* flag = (int*)d_ws;

    detect_dtype_kernel<<<1, 64, 0, stream>>>((const unsigned short*)d_in[1], flag);

    const int blocks = 2048;                     // 8192 waves -> 16 tiles/wave
    ngp_mlp_kernel<<<blocks, 256, 0, stream>>>(d_in[0], d_in[1], d_in[2], d_in[3],
                                               d_in[4], d_in[5], d_in[6], d_in[7],
                                               d_in[8], d_out, flag,
                                               num_tiles, blocks * WPB);
}

// Round 3
// 458.054 us; speedup vs baseline: 1.0645x; 1.0645x over previous
//
#include <hip/hip_runtime.h>
#include <hip/hip_bf16.h>
#include <math.h>

typedef __bf16 bf16_t;
typedef __bf16 bf16x4 __attribute__((ext_vector_type(4)));
typedef __bf16 bf16x8 __attribute__((ext_vector_type(8)));
typedef float  f32x4  __attribute__((ext_vector_type(4)));

#define WPB 4    // waves per block
#define XS  76   // x-scratch row stride (bf16 elements): 152 B, 8B-aligned, conflict-free
#define RS  20   // rgb-scratch row stride (fp32 elements): 80 B -> only 2-way (free) conflicts

// MFMA 16x16x32 layouts (m89/m120-verified):
//   A: lane(m = lane&15, q = lane>>4) holds A[m][8q+j], j=0..7
//   B: lane(n = lane&15, q)           holds B[8q+j][n]
//   C: lane(n = lane&15, q) reg r     holds C[4q+r][n]
//
// Inputs are float32 (confirmed round 2: fp32 path passed, WRITE_SIZE matches
// fp32 outputs exactly). MFMA pipeline is bf16 internally (absmax 0.016 << 0.0716).

__device__ __forceinline__ bf16x8 cvt8(f32x4 lo, f32x4 hi) {
    bf16x8 r;
    #pragma unroll
    for (int j = 0; j < 4; ++j) { r[j] = (bf16_t)lo[j]; r[4 + j] = (bf16_t)hi[j]; }
    return r;
}

__global__ __launch_bounds__(256, 2)   // min 2 waves/EU -> VGPR cap 256: weights stay resident
void ngp_mlp_kernel(const float* __restrict__ feat,
                    const float* __restrict__ W0,
                    const float* __restrict__ b0,
                    const float* __restrict__ W1,
                    const float* __restrict__ b1,
                    const float* __restrict__ Ws,
                    const float* __restrict__ bs,
                    const float* __restrict__ Wr,
                    const float* __restrict__ br,
                    float* __restrict__ out_sigma,
                    float* __restrict__ out_rgb,
                    int num_tiles, int wave_stride)
{
    __shared__ __align__(16) bf16_t xs_all[WPB][16 * XS];
    __shared__ __align__(16) float  rs_all[WPB][16 * RS];

    const int tid  = threadIdx.x;
    const int wid  = tid >> 6;
    const int lane = tid & 63;
    const int n    = lane & 15;
    const int q    = lane >> 4;

    bf16_t* xs = xs_all[wid];
    float*  rs = rs_all[wid];

    // ---------- one-time weight fragment construction (L2/L3-resident) ----------
    bf16x8 w0f[4];                       // W0 [32 x 64], B-frags, K=32 single chunk
    #pragma unroll
    for (int t = 0; t < 4; ++t)
        #pragma unroll
        for (int j = 0; j < 8; ++j)
            w0f[t][j] = (bf16_t)W0[(8*q + j)*64 + 16*t + n];

    bf16x8 w1f[4][2];                    // W1 [64 x 64], 4 col-tiles x 2 K-chunks
    #pragma unroll
    for (int t = 0; t < 4; ++t)
        #pragma unroll
        for (int c = 0; c < 2; ++c)
            #pragma unroll
            for (int j = 0; j < 8; ++j)
                w1f[t][c][j] = (bf16_t)W1[(32*c + 8*q + j)*64 + 16*t + n];

    bf16x8 whf[2][2];                    // heads: tile0 = Wr (16 cols), tile1 col0 = Ws
    #pragma unroll
    for (int c = 0; c < 2; ++c)
        #pragma unroll
        for (int j = 0; j < 8; ++j) {
            whf[0][c][j] = (bf16_t)Wr[(32*c + 8*q + j)*16 + n];
            whf[1][c][j] = (n == 0) ? (bf16_t)Ws[32*c + 8*q + j] : (bf16_t)0.0f;
        }

    float b0v[4], b1v[4];
    #pragma unroll
    for (int t = 0; t < 4; ++t) {
        b0v[t] = b0[16*t + n];
        b1v[t] = b1[16*t + n];
    }
    const float brv = br[n];
    const float bsv = (n == 0) ? (bs[0] - 1.0f) : 0.0f;   // fold the -1 shift

    // ---------- main loop: 16 rows per wave-tile ----------
    int tile = blockIdx.x * WPB + wid;
    if (tile >= num_tiles) return;

    // prefetch first A0 raw fp32: two dwordx4 per lane, coalesced 2 KiB/wave
    const float* fp = feat + (size_t)(tile*16 + n)*32 + 8*q;
    f32x4 aLo = *(const f32x4*)fp;
    f32x4 aHi = *(const f32x4*)(fp + 4);

    while (true) {
        const int  nxt  = tile + wave_stride;
        const bool more = (nxt < num_tiles);
        const int  pf   = more ? nxt : tile;
        const float* fpn = feat + (size_t)(pf*16 + n)*32 + 8*q;
        f32x4 aLoN = *(const f32x4*)fpn;
        f32x4 aHiN = *(const f32x4*)(fpn + 4);

        const int rowbase = tile * 16;
        bf16x8 a0 = cvt8(aLo, aHi);      // adjacent k-pairs in-lane -> v_cvt_pk_bf16_f32

        // ---- layer 0: [16x32] @ [32x64] + b0, ReLU ----
        f32x4 acc0[4];
        #pragma unroll
        for (int t = 0; t < 4; ++t) {
            acc0[t] = (f32x4){b0v[t], b0v[t], b0v[t], b0v[t]};
            acc0[t] = __builtin_amdgcn_mfma_f32_16x16x32_bf16(a0, w0f[t], acc0[t], 0, 0, 0);
        }
        #pragma unroll
        for (int t = 0; t < 4; ++t)
            #pragma unroll
            for (int r = 0; r < 4; ++r)
                xs[(4*q + r)*XS + 16*t + n] = (bf16_t)fmaxf(acc0[t][r], 0.0f);

        // ---- layer 1 A-frags from LDS (2 K-chunks, 2 x b64 each) ----
        bf16x8 a1[2];
        #pragma unroll
        for (int c = 0; c < 2; ++c) {
            union { bf16x8 v; struct { bf16x4 lo, hi; } h; } u;
            u.h.lo = *(const bf16x4*)&xs[n*XS + 32*c + 8*q];
            u.h.hi = *(const bf16x4*)&xs[n*XS + 32*c + 8*q + 4];
            a1[c] = u.v;
        }

        // ---- layer 1: [16x64] @ [64x64] + b1, ReLU ----
        f32x4 acc1[4];
        #pragma unroll
        for (int t = 0; t < 4; ++t) {
            acc1[t] = (f32x4){b1v[t], b1v[t], b1v[t], b1v[t]};
            acc1[t] = __builtin_amdgcn_mfma_f32_16x16x32_bf16(a1[0], w1f[t][0], acc1[t], 0, 0, 0);
            acc1[t] = __builtin_amdgcn_mfma_f32_16x16x32_bf16(a1[1], w1f[t][1], acc1[t], 0, 0, 0);
        }
        #pragma unroll
        for (int t = 0; t < 4; ++t)
            #pragma unroll
            for (int r = 0; r < 4; ++r)
                xs[(4*q + r)*XS + 16*t + n] = (bf16_t)fmaxf(acc1[t][r], 0.0f);

        // ---- heads A-frags ----
        bf16x8 ah[2];
        #pragma unroll
        for (int c = 0; c < 2; ++c) {
            union { bf16x8 v; struct { bf16x4 lo, hi; } h; } u;
            u.h.lo = *(const bf16x4*)&xs[n*XS + 32*c + 8*q];
            u.h.hi = *(const bf16x4*)&xs[n*XS + 32*c + 8*q + 4];
            ah[c] = u.v;
        }

        // ---- heads: rgb = x@Wr + br ; s = x@Ws + bs - 1 ----
        f32x4 aR = (f32x4){brv, brv, brv, brv};
        aR = __builtin_amdgcn_mfma_f32_16x16x32_bf16(ah[0], whf[0][0], aR, 0, 0, 0);
        aR = __builtin_amdgcn_mfma_f32_16x16x32_bf16(ah[1], whf[0][1], aR, 0, 0, 0);
        f32x4 aS = (f32x4){bsv, bsv, bsv, bsv};
        aS = __builtin_amdgcn_mfma_f32_16x16x32_bf16(ah[0], whf[1][0], aS, 0, 0, 0);
        aS = __builtin_amdgcn_mfma_f32_16x16x32_bf16(ah[1], whf[1][1], aS, 0, 0, 0);

        // ---- rgb epilogue: repack via LDS -> coalesced dwordx4 stores (4 KiB/wave) ----
        #pragma unroll
        for (int r = 0; r < 4; ++r)
            rs[(4*q + r)*RS + n] = aR[r];
        {
            f32x4 v = *(const f32x4*)&rs[(lane >> 2)*RS + (lane & 3)*4];
            *(f32x4*)(out_rgb + (size_t)rowbase*16 + 4*lane) = v;
        }

        // ---- sigma epilogue: softplus, dwordx4 from 4 lanes (64 B/tile) ----
        if (n == 0) {
            f32x4 p4;
            #pragma unroll
            for (int r = 0; r < 4; ++r) {
                float z = aS[r];
                p4[r] = fmaxf(z, 0.0f) + log1pf(expf(-fabsf(z)));
            }
            *(f32x4*)(out_sigma + (size_t)rowbase + 4*q) = p4;
        }

        if (!more) break;
        tile = nxt;
        aLo  = aLoN;
        aHi  = aHiN;
    }
}

extern "C" void kernel_launch(void* const* d_in, const int* in_sizes, int n_in,
                              void* d_out, int out_size, void* d_ws, size_t ws_size,
                              hipStream_t stream) {
    const float* feat = (const float*)d_in[0];
    const float* W0   = (const float*)d_in[1];
    const float* b0   = (const float*)d_in[2];
    const float* W1   = (const float*)d_in[3];
    const float* b1   = (const float*)d_in[4];
    const float* Ws   = (const float*)d_in[5];
    const float* bs   = (const float*)d_in[6];
    const float* Wr   = (const float*)d_in[7];
    const float* br   = (const float*)d_in[8];

    const int B         = in_sizes[0] / 32;      // 2,097,152
    const int num_tiles = B / 16;                // 131,072

    float* out_sigma = (float*)d_out;            // [B]
    float* out_rgb   = out_sigma + B;            // [B,16]

    const int blocks = 1024;                     // 4096 waves -> exactly 32 tiles/wave
    ngp_mlp_kernel<<<blocks, 256, 0, stream>>>(feat, W0, b0, W1, b1, Ws, bs, Wr, br,
                                               out_sigma, out_rgb,
                                               num_tiles, blocks * WPB);
}

// Round 4
// 456.123 us; speedup vs baseline: 1.0690x; 1.0042x over previous
//
#include <hip/hip_runtime.h>
#include <hip/hip_bf16.h>
#include <math.h>

typedef __bf16 bf16_t;
typedef __bf16 bf16x4 __attribute__((ext_vector_type(4)));
typedef __bf16 bf16x8 __attribute__((ext_vector_type(8)));
typedef float  f32x4  __attribute__((ext_vector_type(4)));

#define WPB 4    // waves per block
#define XS  76   // x-scratch row stride (bf16 elements): 152 B, 8B-aligned, conflict-free
#define RS  20   // rgb-scratch row stride (fp32 elements): 80 B

// MFMA 16x16x32 layouts (m89/m120-verified):
//   A: lane(m = lane&15, q = lane>>4) holds A[m][8q+j], j=0..7
//   B: lane(n = lane&15, q)           holds B[8q+j][n]
//   C: lane(n = lane&15, q) reg r     holds C[4q+r][n]
//
// Inputs are float32 (confirmed r2). MFMA pipeline bf16 internally (absmax 0.016).
//
// r3 lesson: const/__restrict__ weight loads are invariant -> LLVM RA
// REMATERIALIZES the whole 128-load gather inside the K-loop instead of
// keeping frags resident (VGPR_Count=84, VALUBusy=66%, ~1000 VALU insts/tile).
// pin() makes each fragment opaque to remat so it must stay in VGPRs.

__device__ __forceinline__ void pin(bf16x8& x) {
    f32x4 t = __builtin_bit_cast(f32x4, x);
    asm volatile("" : "+v"(t));
    x = __builtin_bit_cast(bf16x8, t);
}
__device__ __forceinline__ void pinf(float& x) { asm volatile("" : "+v"(x)); }

__device__ __forceinline__ bf16x8 cvt8(f32x4 lo, f32x4 hi) {
    bf16x8 r;
    #pragma unroll
    for (int j = 0; j < 4; ++j) { r[j] = (bf16_t)lo[j]; r[4 + j] = (bf16_t)hi[j]; }
    return r;
}

__global__ __launch_bounds__(256, 2)   // VGPR cap 256: room for ~150 live incl. 64 weight regs
void ngp_mlp_kernel(const float* __restrict__ feat,
                    const float* __restrict__ W0,
                    const float* __restrict__ b0,
                    const float* __restrict__ W1,
                    const float* __restrict__ b1,
                    const float* __restrict__ Ws,
                    const float* __restrict__ bs,
                    const float* __restrict__ Wr,
                    const float* __restrict__ br,
                    float* __restrict__ out_sigma,
                    float* __restrict__ out_rgb,
                    int num_tiles, int wave_stride)
{
    __shared__ __align__(16) bf16_t xs_all[WPB][16 * XS];
    __shared__ __align__(16) float  rs_all[WPB][16 * RS];

    const int tid  = threadIdx.x;
    const int wid  = tid >> 6;
    const int lane = tid & 63;
    const int n    = lane & 15;
    const int q    = lane >> 4;

    bf16_t* xs = xs_all[wid];
    float*  rs = rs_all[wid];

    // ---------- one-time weight fragment construction (L2/L3-resident) ----------
    bf16x8 w0f[4];                       // W0 [32 x 64], B-frags, K=32 single chunk
    #pragma unroll
    for (int t = 0; t < 4; ++t)
        #pragma unroll
        for (int j = 0; j < 8; ++j)
            w0f[t][j] = (bf16_t)W0[(8*q + j)*64 + 16*t + n];

    bf16x8 w1f[4][2];                    // W1 [64 x 64], 4 col-tiles x 2 K-chunks
    #pragma unroll
    for (int t = 0; t < 4; ++t)
        #pragma unroll
        for (int c = 0; c < 2; ++c)
            #pragma unroll
            for (int j = 0; j < 8; ++j)
                w1f[t][c][j] = (bf16_t)W1[(32*c + 8*q + j)*64 + 16*t + n];

    bf16x8 whf[2][2];                    // heads: tile0 = Wr (16 cols), tile1 col0 = Ws
    #pragma unroll
    for (int c = 0; c < 2; ++c)
        #pragma unroll
        for (int j = 0; j < 8; ++j) {
            whf[0][c][j] = (bf16_t)Wr[(32*c + 8*q + j)*16 + n];
            whf[1][c][j] = (n == 0) ? (bf16_t)Ws[32*c + 8*q + j] : (bf16_t)0.0f;
        }

    float b0v[4], b1v[4];
    #pragma unroll
    for (int t = 0; t < 4; ++t) {
        b0v[t] = b0[16*t + n];
        b1v[t] = b1[16*t + n];
    }
    float brv = br[n];
    float bsv = (n == 0) ? (bs[0] - 1.0f) : 0.0f;   // fold the -1 shift

    // ---- pin everything: kill invariant-load rematerialization ----
    #pragma unroll
    for (int t = 0; t < 4; ++t) pin(w0f[t]);
    #pragma unroll
    for (int t = 0; t < 4; ++t)
        #pragma unroll
        for (int c = 0; c < 2; ++c) pin(w1f[t][c]);
    #pragma unroll
    for (int h = 0; h < 2; ++h)
        #pragma unroll
        for (int c = 0; c < 2; ++c) pin(whf[h][c]);
    #pragma unroll
    for (int t = 0; t < 4; ++t) { pinf(b0v[t]); pinf(b1v[t]); }
    pinf(brv); pinf(bsv);

    // ---------- main loop: 16 rows per wave-tile ----------
    int tile = blockIdx.x * WPB + wid;
    if (tile >= num_tiles) return;

    // prefetch first A0 raw fp32: two dwordx4 per lane, coalesced 2 KiB/wave
    const float* fp = feat + (size_t)(tile*16 + n)*32 + 8*q;
    f32x4 aLo = *(const f32x4*)fp;
    f32x4 aHi = *(const f32x4*)(fp + 4);

    while (true) {
        const int  nxt  = tile + wave_stride;
        const bool more = (nxt < num_tiles);
        const int  pf   = more ? nxt : tile;
        const float* fpn = feat + (size_t)(pf*16 + n)*32 + 8*q;
        f32x4 aLoN = *(const f32x4*)fpn;
        f32x4 aHiN = *(const f32x4*)(fpn + 4);

        const int rowbase = tile * 16;
        bf16x8 a0 = cvt8(aLo, aHi);      // adjacent k-pairs in-lane -> v_cvt_pk_bf16_f32

        // ---- layer 0: [16x32] @ [32x64] + b0, ReLU ----
        f32x4 acc0[4];
        #pragma unroll
        for (int t = 0; t < 4; ++t) {
            acc0[t] = (f32x4){b0v[t], b0v[t], b0v[t], b0v[t]};
            acc0[t] = __builtin_amdgcn_mfma_f32_16x16x32_bf16(a0, w0f[t], acc0[t], 0, 0, 0);
        }
        #pragma unroll
        for (int t = 0; t < 4; ++t)
            #pragma unroll
            for (int r = 0; r < 4; ++r)
                xs[(4*q + r)*XS + 16*t + n] = (bf16_t)fmaxf(acc0[t][r], 0.0f);

        // ---- layer 1 A-frags from LDS (2 K-chunks, 2 x b64 each) ----
        bf16x8 a1[2];
        #pragma unroll
        for (int c = 0; c < 2; ++c) {
            union { bf16x8 v; struct { bf16x4 lo, hi; } h; } u;
            u.h.lo = *(const bf16x4*)&xs[n*XS + 32*c + 8*q];
            u.h.hi = *(const bf16x4*)&xs[n*XS + 32*c + 8*q + 4];
            a1[c] = u.v;
        }

        // ---- layer 1: [16x64] @ [64x64] + b1, ReLU ----
        f32x4 acc1[4];
        #pragma unroll
        for (int t = 0; t < 4; ++t) {
            acc1[t] = (f32x4){b1v[t], b1v[t], b1v[t], b1v[t]};
            acc1[t] = __builtin_amdgcn_mfma_f32_16x16x32_bf16(a1[0], w1f[t][0], acc1[t], 0, 0, 0);
            acc1[t] = __builtin_amdgcn_mfma_f32_16x16x32_bf16(a1[1], w1f[t][1], acc1[t], 0, 0, 0);
        }
        #pragma unroll
        for (int t = 0; t < 4; ++t)
            #pragma unroll
            for (int r = 0; r < 4; ++r)
                xs[(4*q + r)*XS + 16*t + n] = (bf16_t)fmaxf(acc1[t][r], 0.0f);

        // ---- heads A-frags ----
        bf16x8 ah[2];
        #pragma unroll
        for (int c = 0; c < 2; ++c) {
            union { bf16x8 v; struct { bf16x4 lo, hi; } h; } u;
            u.h.lo = *(const bf16x4*)&xs[n*XS + 32*c + 8*q];
            u.h.hi = *(const bf16x4*)&xs[n*XS + 32*c + 8*q + 4];
            ah[c] = u.v;
        }

        // ---- heads: rgb = x@Wr + br ; s = x@Ws + bs - 1 ----
        f32x4 aR = (f32x4){brv, brv, brv, brv};
        aR = __builtin_amdgcn_mfma_f32_16x16x32_bf16(ah[0], whf[0][0], aR, 0, 0, 0);
        aR = __builtin_amdgcn_mfma_f32_16x16x32_bf16(ah[1], whf[0][1], aR, 0, 0, 0);
        f32x4 aS = (f32x4){bsv, bsv, bsv, bsv};
        aS = __builtin_amdgcn_mfma_f32_16x16x32_bf16(ah[0], whf[1][0], aS, 0, 0, 0);
        aS = __builtin_amdgcn_mfma_f32_16x16x32_bf16(ah[1], whf[1][1], aS, 0, 0, 0);

        // ---- rgb epilogue: repack via LDS -> coalesced dwordx4 stores (4 KiB/wave) ----
        #pragma unroll
        for (int r = 0; r < 4; ++r)
            rs[(4*q + r)*RS + n] = aR[r];
        {
            f32x4 v = *(const f32x4*)&rs[(lane >> 2)*RS + (lane & 3)*4];
            *(f32x4*)(out_rgb + (size_t)rowbase*16 + 4*lane) = v;
        }

        // ---- sigma epilogue: softplus, dwordx4 from 4 lanes (64 B/tile) ----
        if (n == 0) {
            f32x4 p4;
            #pragma unroll
            for (int r = 0; r < 4; ++r) {
                float z = aS[r];
                p4[r] = fmaxf(z, 0.0f) + log1pf(expf(-fabsf(z)));
            }
            *(f32x4*)(out_sigma + (size_t)rowbase + 4*q) = p4;
        }

        if (!more) break;
        tile = nxt;
        aLo  = aLoN;
        aHi  = aHiN;
    }
}

extern "C" void kernel_launch(void* const* d_in, const int* in_sizes, int n_in,
                              void* d_out, int out_size, void* d_ws, size_t ws_size,
                              hipStream_t stream) {
    const float* feat = (const float*)d_in[0];
    const float* W0   = (const float*)d_in[1];
    const float* b0   = (const float*)d_in[2];
    const float* W1   = (const float*)d_in[3];
    const float* b1   = (const float*)d_in[4];
    const float* Ws   = (const float*)d_in[5];
    const float* bs   = (const float*)d_in[6];
    const float* Wr   = (const float*)d_in[7];
    const float* br   = (const float*)d_in[8];

    const int B         = in_sizes[0] / 32;      // 2,097,152
    const int num_tiles = B / 16;                // 131,072

    float* out_sigma = (float*)d_out;            // [B]
    float* out_rgb   = out_sigma + B;            // [B,16]

    const int blocks = 1024;                     // 4096 waves -> exactly 32 tiles/wave
    ngp_mlp_kernel<<<blocks, 256, 0, stream>>>(feat, W0, b0, W1, b1, Ws, bs, Wr, br,
                                               out_sigma, out_rgb,
                                               num_tiles, blocks * WPB);
}